// Round 8
// baseline (1040.714 us; speedup 1.0000x reference)
//
#include <hip/hip_runtime.h>
#include <hip/hip_bf16.h>
#include <stdint.h>

typedef __bf16 bf16_t;
typedef bf16_t bf16x8 __attribute__((ext_vector_type(8)));
typedef bf16_t bf16x4 __attribute__((ext_vector_type(4)));
typedef float f32x4 __attribute__((ext_vector_type(4)));

#define MFMA16(acc, a, b) __builtin_amdgcn_mfma_f32_16x16x32_bf16((a), (b), (acc), 0, 0, 0)

// light barrier: waits LDS ops only; global register prefetches stay in flight
#define LBAR() do { asm volatile("s_waitcnt lgkmcnt(0)" ::: "memory"); \
  __builtin_amdgcn_s_barrier(); asm volatile("" ::: "memory"); } while (0)

#define NN 16384
#define XC 5000
#define HD 768

// ---------------- prep: LDS-tiled transpose (coalesced read AND write).
// dst layout (elements): W1T[524288] W2T[524288] W3T[262144] gw1T[196608] gw2T[8192]
// 64x64 tiles; [64][65] f32 LDS (pad +1 -> conflict-free transposed read).
__global__ __launch_bounds__(256)
void k_prep_t(const float* __restrict__ W1, const float* __restrict__ W2,
              const float* __restrict__ W3, const float* __restrict__ gw1,
              const float* __restrict__ gw2, bf16_t* __restrict__ dst) {
  __shared__ float tl[64][65];
  int bid = blockIdx.x;
  const float* src; int K, C, Kpad, tk, base, lt;
  if (bid < 128)      { src = W1;  K = 2000; C = 256; Kpad = 2048; tk = 32; base = 0;       lt = bid; }
  else if (bid < 256) { src = W2;  K = 2000; C = 256; Kpad = 2048; tk = 32; base = 524288;  lt = bid - 128; }
  else if (bid < 320) { src = W3;  K = 1000; C = 256; Kpad = 1024; tk = 16; base = 1048576; lt = bid - 256; }
  else if (bid < 368) { src = gw1; K = 768;  C = 256; Kpad = 768;  tk = 12; base = 1310720; lt = bid - 320; }
  else                { src = gw2; K = 256;  C = 32;  Kpad = 256;  tk = 4;  base = 1507328; lt = bid - 368; }
  int tc = lt / tk, tkk = lt - tc * tk;
  int c0 = tc * 64, k0 = tkk * 64;
  int tid = threadIdx.x;
  int cl = tid & 63, rh = tid >> 6;
#pragma unroll
  for (int r = 0; r < 16; ++r) {
    int kp = k0 + r * 4 + rh;
    int c  = c0 + cl;
    float v = (kp < K && c < C) ? src[(size_t)kp * C + c] : 0.0f;   // coalesced in c
    tl[r * 4 + rh][cl] = v;
  }
  __syncthreads();
#pragma unroll
  for (int r = 0; r < 16; ++r) {
    int c = c0 + r * 4 + rh;
    if (c < C) dst[base + (size_t)c * Kpad + k0 + cl] = (bf16_t)tl[cl][r * 4 + rh];  // coalesced in kp
  }
}

// ---------------- stage 1: h[:, br*256+c] = relu(x_slice @ Wbr + bbr)   (bf16 out)
// (round-4 version: dbuf A+B staged, 2-deep reg prefetch, light barriers)
__global__ __launch_bounds__(256, 2)
void k_branch_mlp(const float* __restrict__ x,
                  const bf16_t* __restrict__ W1T, const bf16_t* __restrict__ W2T,
                  const bf16_t* __restrict__ W3T,
                  const float* __restrict__ b1, const float* __restrict__ b2,
                  const float* __restrict__ b3,
                  bf16_t* __restrict__ h) {
  __shared__ __align__(16) bf16_t smem[2 * (64 * 48 + 256 * 48)];  // 61440 B
  bf16_t* A0 = smem;
  bf16_t* B0 = smem + 64 * 48;
  bf16_t* A1 = smem + 64 * 48 + 256 * 48;
  bf16_t* B1 = A1 + 64 * 48;

  const int tid = threadIdx.x;
  const int lane = tid & 63, w = tid >> 6;
  const int ln = lane & 15, g = lane >> 4;
  const int row0 = blockIdx.x * 64;
  const int br = blockIdx.y;

  int Klim, Kpad, Foff;
  const bf16_t* BT; const float* bias;
  if (br == 0)      { Klim = 2000; Kpad = 2048; Foff = 0;    BT = W1T; bias = b1; }
  else if (br == 1) { Klim = 2000; Kpad = 2048; Foff = 2000; BT = W2T; bias = b2; }
  else              { Klim = 1000; Kpad = 1024; Foff = 4000; BT = W3T; bias = b3; }

  const int ar = tid >> 2, akq = tid & 3;  // A row 0..63, 8-f32 quarter
  const float* aptr = x + (size_t)(row0 + ar) * XC + Foff;
  const bf16_t* bptr = BT + (size_t)tid * Kpad;

  f32x4 zz = {0.f, 0.f, 0.f, 0.f};
  f32x4 acc[4][4];
#pragma unroll
  for (int m = 0; m < 4; ++m)
#pragma unroll
    for (int n = 0; n < 4; ++n) acc[m][n] = zz;

  float ra[8]; bf16x8 rb[4];   // reg set A
  float sa[8]; bf16x8 sb[4];   // reg set B

  auto fetchR = [&](int t, float* a, bf16x8* b) {
    int k0 = t * 32;
    int kk = k0 + akq * 8;
    if (kk + 8 <= Klim) {
      float4 v0 = *(const float4*)(aptr + kk);
      float4 v1 = *(const float4*)(aptr + kk + 4);
      a[0]=v0.x; a[1]=v0.y; a[2]=v0.z; a[3]=v0.w;
      a[4]=v1.x; a[5]=v1.y; a[6]=v1.z; a[7]=v1.w;
    } else {
#pragma unroll
      for (int j = 0; j < 8; ++j) a[j] = (kk + j < Klim) ? aptr[kk + j] : 0.0f;
    }
#pragma unroll
    for (int q = 0; q < 4; ++q) b[q] = *(const bf16x8*)(bptr + k0 + q * 8);
  };
  auto stage = [&](const float* a, const bf16x8* b, bf16_t* Ad, bf16_t* Bd) {
    bf16x8 av;
#pragma unroll
    for (int j = 0; j < 8; ++j) av[j] = (bf16_t)a[j];
    *(bf16x8*)&Ad[ar * 48 + akq * 8] = av;
#pragma unroll
    for (int q = 0; q < 4; ++q) *(bf16x8*)&Bd[tid * 48 + q * 8] = b[q];
  };
  auto compute = [&](const bf16_t* Ac, const bf16_t* Bc) {
    bf16x8 af[4], bfr[4];
#pragma unroll
    for (int m = 0; m < 4; ++m) af[m] = *(const bf16x8*)&Ac[(16 * m + ln) * 48 + 8 * g];
#pragma unroll
    for (int n = 0; n < 4; ++n) bfr[n] = *(const bf16x8*)&Bc[(64 * w + 16 * n + ln) * 48 + 8 * g];
#pragma unroll
    for (int m = 0; m < 4; ++m)
#pragma unroll
      for (int n = 0; n < 4; ++n)
        acc[m][n] = MFMA16(acc[m][n], af[m], bfr[n]);
  };

  const int NT = Kpad / 32;  // 64 or 32
  fetchR(0, ra, rb);
  stage(ra, rb, A0, B0);
  fetchR(1, ra, rb);
  fetchR(2, sa, sb);
  LBAR();
  for (int t = 0; t < NT; t += 2) {
    stage(ra, rb, A1, B1);
    if (t + 3 < NT) fetchR(t + 3, ra, rb);
    compute(A0, B0);
    LBAR();
    if (t + 2 < NT) stage(sa, sb, A0, B0);
    if (t + 4 < NT) fetchR(t + 4, sa, sb);
    compute(A1, B1);
    LBAR();
  }

#pragma unroll
  for (int n = 0; n < 4; ++n) {
    int cl = 64 * w + 16 * n + ln;
    float bv = bias[cl];
    int hcol = br * 256 + cl;
#pragma unroll
    for (int m = 0; m < 4; ++m)
#pragma unroll
      for (int i = 0; i < 4; ++i) {
        int rr = row0 + 16 * m + 4 * g + i;
        float v = acc[m][n][i] + bv;
        h[(size_t)rr * HD + hcol] = (bf16_t)(v > 0.f ? v : 0.f);
      }
  }
}

// ---------------- stage 2: t1 = h @ gw1; writes t1T[c][row] (bf16, transposed)
// (round-4 version)
__global__ __launch_bounds__(256, 2)
void k_t1(const bf16_t* __restrict__ h, const bf16_t* __restrict__ gw1T,
          bf16_t* __restrict__ t1T) {
  __shared__ __align__(16) bf16_t smem[2 * (64 * 48 + 256 * 48)];
  bf16_t* A0 = smem;
  bf16_t* B0 = smem + 64 * 48;
  bf16_t* A1 = smem + 64 * 48 + 256 * 48;
  bf16_t* B1 = A1 + 64 * 48;

  const int tid = threadIdx.x;
  const int lane = tid & 63, w = tid >> 6;
  const int ln = lane & 15, g = lane >> 4;
  const int row0 = blockIdx.x * 64;
  const int ar = tid >> 2, akq = tid & 3;
  const bf16_t* aptr = h + (size_t)(row0 + ar) * HD;
  const bf16_t* bptr = gw1T + (size_t)tid * HD;

  f32x4 zz = {0.f, 0.f, 0.f, 0.f};
  f32x4 acc[4][4];
#pragma unroll
  for (int m = 0; m < 4; ++m)
#pragma unroll
    for (int n = 0; n < 4; ++n) acc[m][n] = zz;

  bf16x8 ra; bf16x8 rb[4];
  bf16x8 sa; bf16x8 sb[4];

  auto fetchR = [&](int t, bf16x8& a, bf16x8* b) {
    int k0 = t * 32;
    a = *(const bf16x8*)(aptr + k0 + akq * 8);
#pragma unroll
    for (int q = 0; q < 4; ++q) b[q] = *(const bf16x8*)(bptr + k0 + q * 8);
  };
  auto stage = [&](const bf16x8& a, const bf16x8* b, bf16_t* Ad, bf16_t* Bd) {
    *(bf16x8*)&Ad[ar * 48 + akq * 8] = a;
#pragma unroll
    for (int q = 0; q < 4; ++q) *(bf16x8*)&Bd[tid * 48 + q * 8] = b[q];
  };
  auto compute = [&](const bf16_t* Ac, const bf16_t* Bc) {
    bf16x8 af[4], bfr[4];
#pragma unroll
    for (int m = 0; m < 4; ++m) af[m] = *(const bf16x8*)&Ac[(16 * m + ln) * 48 + 8 * g];
#pragma unroll
    for (int n = 0; n < 4; ++n) bfr[n] = *(const bf16x8*)&Bc[(64 * w + 16 * n + ln) * 48 + 8 * g];
#pragma unroll
    for (int m = 0; m < 4; ++m)
#pragma unroll
      for (int n = 0; n < 4; ++n)
        acc[m][n] = MFMA16(acc[m][n], af[m], bfr[n]);
  };

  const int NT = HD / 32;  // 24
  fetchR(0, ra, rb);
  stage(ra, rb, A0, B0);
  fetchR(1, ra, rb);
  fetchR(2, sa, sb);
  LBAR();
  for (int t = 0; t < NT; t += 2) {
    stage(ra, rb, A1, B1);
    if (t + 3 < NT) fetchR(t + 3, ra, rb);
    compute(A0, B0);
    LBAR();
    if (t + 2 < NT) stage(sa, sb, A0, B0);
    if (t + 4 < NT) fetchR(t + 4, sa, sb);
    compute(A1, B1);
    LBAR();
  }

#pragma unroll
  for (int n = 0; n < 4; ++n) {
    int c = 64 * w + 16 * n + ln;
#pragma unroll
    for (int m = 0; m < 4; ++m) {
      bf16x4 p;
#pragma unroll
      for (int i = 0; i < 4; ++i) p[i] = (bf16_t)acc[m][n][i];
      *(bf16x4*)(t1T + (size_t)c * NN + row0 + 16 * m + 4 * g) = p;
    }
  }
}

// ---------------- stage 3a: partial[kh] = adj[:, khalf] @ t1[khalf, :]
// (round-6 version, unchanged)
__global__ __launch_bounds__(512)
void k_gcn1a(const float* __restrict__ adj, const bf16_t* __restrict__ t1T,
             float* __restrict__ part) {
  __shared__ __align__(16) bf16_t smem[2 * 128 * 48];   // 24576 B
  bf16_t* A0 = smem;
  bf16_t* A1 = smem + 128 * 48;

  const int tid = threadIdx.x;
  const int lane = tid & 63, w = tid >> 6;      // w: 0..7
  const int ln = lane & 15, g = lane >> 4;

  const int bid = blockIdx.x;
  const int xcd = bid & 7, slot = bid >> 3;
  const int kh = xcd >> 2;                      // K-half: 0 for XCD 0-3, 1 for 4-7
  const int rb = slot * 4 + (xcd & 3);          // row-block 0..127
  const int row0 = rb * 128;
  const int kbase = kh * 8192;

  const int ar = tid >> 2, akq = tid & 3;       // A: row 0..127, 8-f32 chunk 0..3
  const float*  aptr = adj + (size_t)(row0 + ar) * NN + kbase + akq * 8;
  const bf16_t* bB = t1T + (size_t)(32 * w + ln) * NN + kbase + 8 * g;

  f32x4 zz = {0.f, 0.f, 0.f, 0.f};
  f32x4 acc[8][2];
#pragma unroll
  for (int m = 0; m < 8; ++m) { acc[m][0] = zz; acc[m][1] = zz; }

  float aX[8], aY[8];
  bf16x8 bR0, bR1, bS0, bS1;

  auto fetchA = [&](int t, float* a) {
    const float* p = aptr + t * 32;
    float4 v0 = *(const float4*)(p);
    float4 v1 = *(const float4*)(p + 4);
    a[0]=v0.x; a[1]=v0.y; a[2]=v0.z; a[3]=v0.w;
    a[4]=v1.x; a[5]=v1.y; a[6]=v1.z; a[7]=v1.w;
  };
  auto fetchB = [&](int t, bf16x8& b0, bf16x8& b1) {
    int k0 = t * 32;
    b0 = *(const bf16x8*)(bB + k0);
    b1 = *(const bf16x8*)(bB + (size_t)16 * NN + k0);
  };
  auto stageA = [&](const float* a, bf16_t* Ad) {
    bf16x8 av;
#pragma unroll
    for (int j = 0; j < 8; ++j) av[j] = (bf16_t)a[j];
    *(bf16x8*)&Ad[ar * 48 + akq * 8] = av;
  };
  auto compute = [&](const bf16_t* Ac, const bf16x8& b0, const bf16x8& b1) {
#pragma unroll
    for (int m = 0; m < 8; ++m) {
      bf16x8 af = *(const bf16x8*)&Ac[(16 * m + ln) * 48 + 8 * g];
      acc[m][0] = MFMA16(acc[m][0], af, b0);
      acc[m][1] = MFMA16(acc[m][1], af, b1);
    }
  };

  const int NT = 8192 / 32;  // 256
  fetchA(0, aX); stageA(aX, A0);
  fetchA(1, aX); fetchA(2, aY);
  fetchB(0, bR0, bR1); fetchB(1, bS0, bS1);
  LBAR();
  for (int t = 0; t < NT; t += 2) {
    stageA(aX, A1);
    if (t + 3 < NT) fetchA(t + 3, aX);
    compute(A0, bR0, bR1);
    if (t + 2 < NT) fetchB(t + 2, bR0, bR1);
    LBAR();
    stageA(aY, A0);
    if (t + 4 < NT) fetchA(t + 4, aY);
    compute(A1, bS0, bS1);
    if (t + 3 < NT) fetchB(t + 3, bS0, bS1);
    LBAR();
  }

  // write f32 partials: part[kh][row][col]
  float* pp = part + (size_t)kh * NN * 256;
#pragma unroll
  for (int n = 0; n < 2; ++n) {
    int cl = 32 * w + 16 * n + ln;
#pragma unroll
    for (int m = 0; m < 8; ++m)
#pragma unroll
      for (int i = 0; i < 4; ++i) {
        int rr = row0 + 16 * m + 4 * g + i;
        pp[(size_t)rr * 256 + cl] = acc[m][n][i];
      }
  }
}

// ---------------- stage 3b: g1 = relu(p0+p1+gb1); t2 = g1 @ gw2; write t2T
// (round-6 version, unchanged)
__global__ __launch_bounds__(256)
void k_gcn1b(const float* __restrict__ part, const float* __restrict__ gb1,
             const bf16_t* __restrict__ gw2T, bf16_t* __restrict__ t2T) {
  __shared__ __align__(16) bf16_t g1s[64 * 264];   // 33792 B
  __shared__ __align__(16) bf16_t w2s[32 * 264];   // 16896 B
  const int tid = threadIdx.x;
  const int lane = tid & 63, w = tid >> 6;         // w: 0..3
  const int ln = lane & 15, g = lane >> 4;
  const int row0 = blockIdx.x * 64;

  for (int i = tid; i < 32 * 256; i += 256) {
    int rr = i >> 8, s = i & 255;
    w2s[rr * 264 + s] = gw2T[i];
  }

  {
    const int r = tid >> 2, q = tid & 3, c0 = q * 64;
    const float* p0 = part + (size_t)(row0 + r) * 256 + c0;
    const float* p1 = p0 + (size_t)NN * 256;
#pragma unroll
    for (int j = 0; j < 8; ++j) {
      int c = c0 + j * 8;
      float4 u0 = *(const float4*)(p0 + j * 8);
      float4 u1 = *(const float4*)(p0 + j * 8 + 4);
      float4 v0 = *(const float4*)(p1 + j * 8);
      float4 v1 = *(const float4*)(p1 + j * 8 + 4);
      float4 g0 = *(const float4*)(gb1 + c);
      float4 g1v = *(const float4*)(gb1 + c + 4);
      bf16x8 o;
      float t0 = u0.x + v0.x + g0.x; o[0] = (bf16_t)(t0 > 0.f ? t0 : 0.f);
      float t1 = u0.y + v0.y + g0.y; o[1] = (bf16_t)(t1 > 0.f ? t1 : 0.f);
      float t2 = u0.z + v0.z + g0.z; o[2] = (bf16_t)(t2 > 0.f ? t2 : 0.f);
      float t3 = u0.w + v0.w + g0.w; o[3] = (bf16_t)(t3 > 0.f ? t3 : 0.f);
      float t4 = u1.x + v1.x + g1v.x; o[4] = (bf16_t)(t4 > 0.f ? t4 : 0.f);
      float t5 = u1.y + v1.y + g1v.y; o[5] = (bf16_t)(t5 > 0.f ? t5 : 0.f);
      float t6 = u1.z + v1.z + g1v.z; o[6] = (bf16_t)(t6 > 0.f ? t6 : 0.f);
      float t7 = u1.w + v1.w + g1v.w; o[7] = (bf16_t)(t7 > 0.f ? t7 : 0.f);
      *(bf16x8*)&g1s[r * 264 + c] = o;
    }
  }
  __syncthreads();

  f32x4 zz = {0.f, 0.f, 0.f, 0.f};
#pragma unroll
  for (int n = 0; n < 2; ++n) {
    f32x4 macc = zz;
#pragma unroll
    for (int ks = 0; ks < 8; ++ks) {
      bf16x8 ag = *(const bf16x8*)&g1s[(16 * w + ln) * 264 + ks * 32 + 8 * g];
      bf16x8 bg = *(const bf16x8*)&w2s[(16 * n + ln) * 264 + ks * 32 + 8 * g];
      macc = MFMA16(macc, ag, bg);
    }
    int c2 = 16 * n + ln;
    bf16x4 p;
#pragma unroll
    for (int i = 0; i < 4; ++i) p[i] = (bf16_t)macc[i];
    *(bf16x4*)(t2T + (size_t)c2 * NN + row0 + 16 * w + 4 * g) = p;
  }
}

// ---------------- stage 4: out = log_softmax(adj @ t2 + gb2)
// (round-4/6 version, unchanged; measured 203 us in round 7)
__global__ __launch_bounds__(256, 2)
void k_gcn2(const float* __restrict__ adj, const bf16_t* __restrict__ t2T,
            const float* __restrict__ gb2, float* __restrict__ out) {
  __shared__ __align__(16) char smem[49152];
  float* Lg = (float*)smem;
  const int tid = threadIdx.x;
  const int lane = tid & 63, w = tid >> 6;
  const int ln = lane & 15, g = lane >> 4;
  const int row0 = blockIdx.x * 32;

  bf16_t* A0 = (bf16_t*)(smem + w * 12288);
  bf16_t* B0 = (bf16_t*)(smem + w * 12288 + 3072);
  bf16_t* A1 = (bf16_t*)(smem + w * 12288 + 6144);
  bf16_t* B1 = (bf16_t*)(smem + w * 12288 + 9216);

  const int ar = lane >> 1, akq = lane & 1;
  const float*  aptr = adj + (size_t)(row0 + ar) * NN + akq * 16;
  const bf16_t* bptr = t2T + (size_t)ar * NN + akq * 16;

  f32x4 zz = {0.f, 0.f, 0.f, 0.f};
  f32x4 macc[2][2];
#pragma unroll
  for (int m = 0; m < 2; ++m) { macc[m][0] = zz; macc[m][1] = zz; }

  const int kb0 = w * 4096;

  float4 ra0, ra1, ra2, ra3; bf16x8 rab0, rab1;
  float4 sa0, sa1, sa2, sa3; bf16x8 sbb0, sbb1;

  auto fetchR = [&](int s, float4& a0, float4& a1, float4& a2, float4& a3,
                    bf16x8& b0, bf16x8& b1) {
    int kb = kb0 + s * 32;
    a0 = *(const float4*)(aptr + kb);
    a1 = *(const float4*)(aptr + kb + 4);
    a2 = *(const float4*)(aptr + kb + 8);
    a3 = *(const float4*)(aptr + kb + 12);
    b0 = *(const bf16x8*)(bptr + kb);
    b1 = *(const bf16x8*)(bptr + kb + 8);
  };
  auto body = [&](const float4& a0, const float4& a1, const float4& a2, const float4& a3,
                  const bf16x8& b0, const bf16x8& b1, bf16_t* Ab, bf16_t* Bb) {
    bf16x8 av0, av1;
    av0[0]=(bf16_t)a0.x; av0[1]=(bf16_t)a0.y; av0[2]=(bf16_t)a0.z; av0[3]=(bf16_t)a0.w;
    av0[4]=(bf16_t)a1.x; av0[5]=(bf16_t)a1.y; av0[6]=(bf16_t)a1.z; av0[7]=(bf16_t)a1.w;
    av1[0]=(bf16_t)a2.x; av1[1]=(bf16_t)a2.y; av1[2]=(bf16_t)a2.z; av1[3]=(bf16_t)a2.w;
    av1[4]=(bf16_t)a3.x; av1[5]=(bf16_t)a3.y; av1[6]=(bf16_t)a3.z; av1[7]=(bf16_t)a3.w;
    *(bf16x8*)&Ab[ar * 48 + akq * 16] = av0;
    *(bf16x8*)&Ab[ar * 48 + akq * 16 + 8] = av1;
    *(bf16x8*)&Bb[ar * 48 + akq * 16] = b0;
    *(bf16x8*)&Bb[ar * 48 + akq * 16 + 8] = b1;
    bf16x8 af[2], bfr[2];
#pragma unroll
    for (int m = 0; m < 2; ++m) af[m] = *(const bf16x8*)&Ab[(16 * m + ln) * 48 + 8 * g];
#pragma unroll
    for (int n = 0; n < 2; ++n) bfr[n] = *(const bf16x8*)&Bb[(16 * n + ln) * 48 + 8 * g];
#pragma unroll
    for (int m = 0; m < 2; ++m)
#pragma unroll
      for (int n = 0; n < 2; ++n)
        macc[m][n] = MFMA16(macc[m][n], af[m], bfr[n]);
  };

  fetchR(0, ra0, ra1, ra2, ra3, rab0, rab1);
  fetchR(1, sa0, sa1, sa2, sa3, sbb0, sbb1);

  for (int s = 0; s < 128; s += 2) {
    {
      bf16x8 tb0 = rab0, tb1 = rab1;
      float4 t0 = ra0, t1 = ra1, t2 = ra2, t3 = ra3;
      if (s + 2 < 128) fetchR(s + 2, ra0, ra1, ra2, ra3, rab0, rab1);
      body(t0, t1, t2, t3, tb0, tb1, A0, B0);
    }
    {
      bf16x8 tb0 = sbb0, tb1 = sbb1;
      float4 t0 = sa0, t1 = sa1, t2 = sa2, t3 = sa3;
      if (s + 3 < 128) fetchR(s + 3, sa0, sa1, sa2, sa3, sbb0, sbb1);
      body(t0, t1, t2, t3, tb0, tb1, A1, B1);
    }
  }

  __syncthreads();
#pragma unroll
  for (int m = 0; m < 2; ++m)
#pragma unroll
    for (int n = 0; n < 2; ++n)
#pragma unroll
      for (int i = 0; i < 4; ++i) {
        int rl = 16 * m + 4 * g + i;
        int cl = 16 * n + ln;
        Lg[(w * 32 + rl) * 32 + cl] = macc[m][n][i];
      }
  __syncthreads();

  int rr = tid >> 3, cg = tid & 7;
  float l4[4];
#pragma unroll
  for (int j = 0; j < 4; ++j) {
    int c = cg * 4 + j;
    l4[j] = Lg[rr * 32 + c] + Lg[(32 + rr) * 32 + c] +
            Lg[(64 + rr) * 32 + c] + Lg[(96 + rr) * 32 + c] + gb2[c];
  }
  float mx = fmaxf(fmaxf(l4[0], l4[1]), fmaxf(l4[2], l4[3]));
  mx = fmaxf(mx, __shfl_xor(mx, 1));
  mx = fmaxf(mx, __shfl_xor(mx, 2));
  mx = fmaxf(mx, __shfl_xor(mx, 4));
  float se = 0.f;
#pragma unroll
  for (int j = 0; j < 4; ++j) se += expf(l4[j] - mx);
  se += __shfl_xor(se, 1);
  se += __shfl_xor(se, 2);
  se += __shfl_xor(se, 4);
  float lse = mx + logf(se);
  float4 o;
  o.x = l4[0] - lse; o.y = l4[1] - lse; o.z = l4[2] - lse; o.w = l4[3] - lse;
  *(float4*)&out[(size_t)(row0 + rr) * 32 + cg * 4] = o;
}

extern "C" void kernel_launch(void* const* d_in, const int* in_sizes, int n_in,
                              void* d_out, int out_size, void* d_ws, size_t ws_size,
                              hipStream_t stream) {
  const float* x   = (const float*)d_in[0];
  const float* adj = (const float*)d_in[1];
  const float* W1  = (const float*)d_in[2];
  const float* b1  = (const float*)d_in[3];
  const float* W2  = (const float*)d_in[4];
  const float* b2  = (const float*)d_in[5];
  const float* W3  = (const float*)d_in[6];
  const float* b3  = (const float*)d_in[7];
  const float* gw1 = (const float*)d_in[8];
  const float* gb1 = (const float*)d_in[9];
  const float* gw2 = (const float*)d_in[10];
  const float* gb2 = (const float*)d_in[11];
  float* out = (float*)d_out;

  char* ws = (char*)d_ws;
  size_t off = 0;
  auto alloc = [&](size_t bytes) { char* p = ws + off; off += (bytes + 255) & ~(size_t)255; return p; };
  bf16_t* W1T  = (bf16_t*)alloc((size_t)256 * 2048 * 2);
  bf16_t* W2T  = (bf16_t*)alloc((size_t)256 * 2048 * 2);
  bf16_t* W3T  = (bf16_t*)alloc((size_t)256 * 1024 * 2);
  bf16_t* gw1T = (bf16_t*)alloc((size_t)256 * 768 * 2);
  bf16_t* gw2T = (bf16_t*)alloc((size_t)32 * 256 * 2);
  bf16_t* h    = (bf16_t*)alloc((size_t)NN * HD * 2);
  bf16_t* t1T  = (bf16_t*)alloc((size_t)256 * NN * 2);
  bf16_t* t2T  = (bf16_t*)alloc((size_t)32 * NN * 2);
  float*  part = (float*)alloc((size_t)2 * NN * 256 * 4);   // 32 MB f32 partials
  (void)W2T; (void)W3T;
  if (ws_size < off) return;

  k_prep_t<<<372, 256, 0, stream>>>(W1, W2, W3, gw1, gw2, W1T);

  k_branch_mlp<<<dim3(256, 3), 256, 0, stream>>>(x, W1T, W2T, W3T, b1, b2, b3, h);
  k_t1<<<256, 256, 0, stream>>>(h, gw1T, t1T);
  // DIAGNOSTIC duplicate: idempotent (writes identical partials twice).
  // dur_us delta vs (round6 - prep fix) == exact k_gcn1a duration.
  k_gcn1a<<<256, 512, 0, stream>>>(adj, t1T, part);
  k_gcn1a<<<256, 512, 0, stream>>>(adj, t1T, part);
  k_gcn1b<<<256, 256, 0, stream>>>(part, gb1, gw2T, t2T);
  k_gcn2<<<512, 256, 0, stream>>>(adj, t2T, gb2, out);
}

// Round 9
// 705.213 us; speedup vs baseline: 1.4757x; 1.4757x over previous
//
#include <hip/hip_runtime.h>
#include <hip/hip_bf16.h>
#include <stdint.h>

typedef __bf16 bf16_t;
typedef bf16_t bf16x8 __attribute__((ext_vector_type(8)));
typedef bf16_t bf16x4 __attribute__((ext_vector_type(4)));
typedef float f32x4 __attribute__((ext_vector_type(4)));

#define MFMA16(acc, a, b) __builtin_amdgcn_mfma_f32_16x16x32_bf16((a), (b), (acc), 0, 0, 0)

// light barrier: waits LDS ops only; global register prefetches stay in flight
#define LBAR() do { asm volatile("s_waitcnt lgkmcnt(0)" ::: "memory"); \
  __builtin_amdgcn_s_barrier(); asm volatile("" ::: "memory"); } while (0)

#define NN 16384
#define XC 5000
#define HD 768

// ---------------- prep: LDS-tiled transpose (coalesced read AND write).
__global__ __launch_bounds__(256)
void k_prep_t(const float* __restrict__ W1, const float* __restrict__ W2,
              const float* __restrict__ W3, const float* __restrict__ gw1,
              const float* __restrict__ gw2, bf16_t* __restrict__ dst) {
  __shared__ float tl[64][65];
  int bid = blockIdx.x;
  const float* src; int K, C, Kpad, tk, base, lt;
  if (bid < 128)      { src = W1;  K = 2000; C = 256; Kpad = 2048; tk = 32; base = 0;       lt = bid; }
  else if (bid < 256) { src = W2;  K = 2000; C = 256; Kpad = 2048; tk = 32; base = 524288;  lt = bid - 128; }
  else if (bid < 320) { src = W3;  K = 1000; C = 256; Kpad = 1024; tk = 16; base = 1048576; lt = bid - 256; }
  else if (bid < 368) { src = gw1; K = 768;  C = 256; Kpad = 768;  tk = 12; base = 1310720; lt = bid - 320; }
  else                { src = gw2; K = 256;  C = 32;  Kpad = 256;  tk = 4;  base = 1507328; lt = bid - 368; }
  int tc = lt / tk, tkk = lt - tc * tk;
  int c0 = tc * 64, k0 = tkk * 64;
  int tid = threadIdx.x;
  int cl = tid & 63, rh = tid >> 6;
#pragma unroll
  for (int r = 0; r < 16; ++r) {
    int kp = k0 + r * 4 + rh;
    int c  = c0 + cl;
    float v = (kp < K && c < C) ? src[(size_t)kp * C + c] : 0.0f;   // coalesced in c
    tl[r * 4 + rh][cl] = v;
  }
  __syncthreads();
#pragma unroll
  for (int r = 0; r < 16; ++r) {
    int c = c0 + r * 4 + rh;
    if (c < C) dst[base + (size_t)c * Kpad + k0 + cl] = (bf16_t)tl[cl][r * 4 + rh];  // coalesced in kp
  }
}

// ---------------- stage 1: h[:, br*256+c] = relu(x_slice @ Wbr + bbr)   (bf16 out)
__global__ __launch_bounds__(256, 2)
void k_branch_mlp(const float* __restrict__ x,
                  const bf16_t* __restrict__ W1T, const bf16_t* __restrict__ W2T,
                  const bf16_t* __restrict__ W3T,
                  const float* __restrict__ b1, const float* __restrict__ b2,
                  const float* __restrict__ b3,
                  bf16_t* __restrict__ h) {
  __shared__ __align__(16) bf16_t smem[2 * (64 * 48 + 256 * 48)];  // 61440 B
  bf16_t* A0 = smem;
  bf16_t* B0 = smem + 64 * 48;
  bf16_t* A1 = smem + 64 * 48 + 256 * 48;
  bf16_t* B1 = A1 + 64 * 48;

  const int tid = threadIdx.x;
  const int lane = tid & 63, w = tid >> 6;
  const int ln = lane & 15, g = lane >> 4;
  const int row0 = blockIdx.x * 64;
  const int br = blockIdx.y;

  int Klim, Kpad, Foff;
  const bf16_t* BT; const float* bias;
  if (br == 0)      { Klim = 2000; Kpad = 2048; Foff = 0;    BT = W1T; bias = b1; }
  else if (br == 1) { Klim = 2000; Kpad = 2048; Foff = 2000; BT = W2T; bias = b2; }
  else              { Klim = 1000; Kpad = 1024; Foff = 4000; BT = W3T; bias = b3; }

  const int ar = tid >> 2, akq = tid & 3;  // A row 0..63, 8-f32 quarter
  const float* aptr = x + (size_t)(row0 + ar) * XC + Foff;
  const bf16_t* bptr = BT + (size_t)tid * Kpad;

  f32x4 zz = {0.f, 0.f, 0.f, 0.f};
  f32x4 acc[4][4];
#pragma unroll
  for (int m = 0; m < 4; ++m)
#pragma unroll
    for (int n = 0; n < 4; ++n) acc[m][n] = zz;

  float ra[8]; bf16x8 rb[4];   // reg set A
  float sa[8]; bf16x8 sb[4];   // reg set B

  auto fetchR = [&](int t, float* a, bf16x8* b) {
    int k0 = t * 32;
    int kk = k0 + akq * 8;
    if (kk + 8 <= Klim) {
      float4 v0 = *(const float4*)(aptr + kk);
      float4 v1 = *(const float4*)(aptr + kk + 4);
      a[0]=v0.x; a[1]=v0.y; a[2]=v0.z; a[3]=v0.w;
      a[4]=v1.x; a[5]=v1.y; a[6]=v1.z; a[7]=v1.w;
    } else {
#pragma unroll
      for (int j = 0; j < 8; ++j) a[j] = (kk + j < Klim) ? aptr[kk + j] : 0.0f;
    }
#pragma unroll
    for (int q = 0; q < 4; ++q) b[q] = *(const bf16x8*)(bptr + k0 + q * 8);
  };
  auto stage = [&](const float* a, const bf16x8* b, bf16_t* Ad, bf16_t* Bd) {
    bf16x8 av;
#pragma unroll
    for (int j = 0; j < 8; ++j) av[j] = (bf16_t)a[j];
    *(bf16x8*)&Ad[ar * 48 + akq * 8] = av;
#pragma unroll
    for (int q = 0; q < 4; ++q) *(bf16x8*)&Bd[tid * 48 + q * 8] = b[q];
  };
  auto compute = [&](const bf16_t* Ac, const bf16_t* Bc) {
    bf16x8 af[4], bfr[4];
#pragma unroll
    for (int m = 0; m < 4; ++m) af[m] = *(const bf16x8*)&Ac[(16 * m + ln) * 48 + 8 * g];
#pragma unroll
    for (int n = 0; n < 4; ++n) bfr[n] = *(const bf16x8*)&Bc[(64 * w + 16 * n + ln) * 48 + 8 * g];
#pragma unroll
    for (int m = 0; m < 4; ++m)
#pragma unroll
      for (int n = 0; n < 4; ++n)
        acc[m][n] = MFMA16(acc[m][n], af[m], bfr[n]);
  };

  const int NT = Kpad / 32;  // 64 or 32
  fetchR(0, ra, rb);
  stage(ra, rb, A0, B0);
  fetchR(1, ra, rb);
  fetchR(2, sa, sb);
  LBAR();
  for (int t = 0; t < NT; t += 2) {
    stage(ra, rb, A1, B1);
    if (t + 3 < NT) fetchR(t + 3, ra, rb);
    compute(A0, B0);
    LBAR();
    if (t + 2 < NT) stage(sa, sb, A0, B0);
    if (t + 4 < NT) fetchR(t + 4, sa, sb);
    compute(A1, B1);
    LBAR();
  }

#pragma unroll
  for (int n = 0; n < 4; ++n) {
    int cl = 64 * w + 16 * n + ln;
    float bv = bias[cl];
    int hcol = br * 256 + cl;
#pragma unroll
    for (int m = 0; m < 4; ++m)
#pragma unroll
      for (int i = 0; i < 4; ++i) {
        int rr = row0 + 16 * m + 4 * g + i;
        float v = acc[m][n][i] + bv;
        h[(size_t)rr * HD + hcol] = (bf16_t)(v > 0.f ? v : 0.f);
      }
  }
}

// ---------------- stage 2: t1 = h @ gw1; writes t1T[c][row] (bf16, transposed)
__global__ __launch_bounds__(256, 2)
void k_t1(const bf16_t* __restrict__ h, const bf16_t* __restrict__ gw1T,
          bf16_t* __restrict__ t1T) {
  __shared__ __align__(16) bf16_t smem[2 * (64 * 48 + 256 * 48)];
  bf16_t* A0 = smem;
  bf16_t* B0 = smem + 64 * 48;
  bf16_t* A1 = smem + 64 * 48 + 256 * 48;
  bf16_t* B1 = A1 + 64 * 48;

  const int tid = threadIdx.x;
  const int lane = tid & 63, w = tid >> 6;
  const int ln = lane & 15, g = lane >> 4;
  const int row0 = blockIdx.x * 64;
  const int ar = tid >> 2, akq = tid & 3;
  const bf16_t* aptr = h + (size_t)(row0 + ar) * HD;
  const bf16_t* bptr = gw1T + (size_t)tid * HD;

  f32x4 zz = {0.f, 0.f, 0.f, 0.f};
  f32x4 acc[4][4];
#pragma unroll
  for (int m = 0; m < 4; ++m)
#pragma unroll
    for (int n = 0; n < 4; ++n) acc[m][n] = zz;

  bf16x8 ra; bf16x8 rb[4];
  bf16x8 sa; bf16x8 sb[4];

  auto fetchR = [&](int t, bf16x8& a, bf16x8* b) {
    int k0 = t * 32;
    a = *(const bf16x8*)(aptr + k0 + akq * 8);
#pragma unroll
    for (int q = 0; q < 4; ++q) b[q] = *(const bf16x8*)(bptr + k0 + q * 8);
  };
  auto stage = [&](const bf16x8& a, const bf16x8* b, bf16_t* Ad, bf16_t* Bd) {
    *(bf16x8*)&Ad[ar * 48 + akq * 8] = a;
#pragma unroll
    for (int q = 0; q < 4; ++q) *(bf16x8*)&Bd[tid * 48 + q * 8] = b[q];
  };
  auto compute = [&](const bf16_t* Ac, const bf16_t* Bc) {
    bf16x8 af[4], bfr[4];
#pragma unroll
    for (int m = 0; m < 4; ++m) af[m] = *(const bf16x8*)&Ac[(16 * m + ln) * 48 + 8 * g];
#pragma unroll
    for (int n = 0; n < 4; ++n) bfr[n] = *(const bf16x8*)&Bc[(64 * w + 16 * n + ln) * 48 + 8 * g];
#pragma unroll
    for (int m = 0; m < 4; ++m)
#pragma unroll
      for (int n = 0; n < 4; ++n)
        acc[m][n] = MFMA16(acc[m][n], af[m], bfr[n]);
  };

  const int NT = HD / 32;  // 24
  fetchR(0, ra, rb);
  stage(ra, rb, A0, B0);
  fetchR(1, ra, rb);
  fetchR(2, sa, sb);
  LBAR();
  for (int t = 0; t < NT; t += 2) {
    stage(ra, rb, A1, B1);
    if (t + 3 < NT) fetchR(t + 3, ra, rb);
    compute(A0, B0);
    LBAR();
    if (t + 2 < NT) stage(sa, sb, A0, B0);
    if (t + 4 < NT) fetchR(t + 4, sa, sb);
    compute(A1, B1);
    LBAR();
  }

#pragma unroll
  for (int n = 0; n < 4; ++n) {
    int c = 64 * w + 16 * n + ln;
#pragma unroll
    for (int m = 0; m < 4; ++m) {
      bf16x4 p;
#pragma unroll
      for (int i = 0; i < 4; ++i) p[i] = (bf16_t)acc[m][n][i];
      *(bf16x4*)(t1T + (size_t)c * NN + row0 + 16 * m + 4 * g) = p;
    }
  }
}

// ---------------- stage 3a: partial[kp] = adj[:, kslice] @ t1[kslice, :]
// 512 thr (8 waves), BM=128, K=4096/block, grid 512 (128 rb x 4 kp).
// kp = (bid&7)>>1: under %8 XCD round-robin each XCD touches ONE 2 MB t1T
// slice (half its L2) -> slice survives adj streaming; 64 blocks reuse it.
__global__ __launch_bounds__(512)
void k_gcn1a(const float* __restrict__ adj, const bf16_t* __restrict__ t1T,
             float* __restrict__ part) {
  __shared__ __align__(16) bf16_t smem[2 * 128 * 48];   // 24576 B
  bf16_t* A0 = smem;
  bf16_t* A1 = smem + 128 * 48;

  const int tid = threadIdx.x;
  const int lane = tid & 63, w = tid >> 6;      // w: 0..7
  const int ln = lane & 15, g = lane >> 4;

  const int bid = blockIdx.x;
  const int x7 = bid & 7;
  const int kp = x7 >> 1;                       // K-slice 0..3 (pinned per XCD)
  const int rb = (bid >> 3) * 2 + (x7 & 1);     // row-block 0..127
  const int row0 = rb * 128;
  const int kbase = kp * 4096;

  const int ar = tid >> 2, akq = tid & 3;       // A: row 0..127, 8-f32 chunk 0..3
  const float*  aptr = adj + (size_t)(row0 + ar) * NN + kbase + akq * 8;
  const bf16_t* bB = t1T + (size_t)(32 * w + ln) * NN + kbase + 8 * g;

  f32x4 zz = {0.f, 0.f, 0.f, 0.f};
  f32x4 acc[8][2];
#pragma unroll
  for (int m = 0; m < 8; ++m) { acc[m][0] = zz; acc[m][1] = zz; }

  float aX[8], aY[8];
  bf16x8 bR0, bR1, bS0, bS1;

  auto fetchA = [&](int t, float* a) {
    const float* p = aptr + t * 32;
    float4 v0 = *(const float4*)(p);
    float4 v1 = *(const float4*)(p + 4);
    a[0]=v0.x; a[1]=v0.y; a[2]=v0.z; a[3]=v0.w;
    a[4]=v1.x; a[5]=v1.y; a[6]=v1.z; a[7]=v1.w;
  };
  auto fetchB = [&](int t, bf16x8& b0, bf16x8& b1) {
    int k0 = t * 32;
    b0 = *(const bf16x8*)(bB + k0);
    b1 = *(const bf16x8*)(bB + (size_t)16 * NN + k0);
  };
  auto stageA = [&](const float* a, bf16_t* Ad) {
    bf16x8 av;
#pragma unroll
    for (int j = 0; j < 8; ++j) av[j] = (bf16_t)a[j];
    *(bf16x8*)&Ad[ar * 48 + akq * 8] = av;
  };
  auto compute = [&](const bf16_t* Ac, const bf16x8& b0, const bf16x8& b1) {
#pragma unroll
    for (int m = 0; m < 8; ++m) {
      bf16x8 af = *(const bf16x8*)&Ac[(16 * m + ln) * 48 + 8 * g];
      acc[m][0] = MFMA16(acc[m][0], af, b0);
      acc[m][1] = MFMA16(acc[m][1], af, b1);
    }
  };

  const int NT = 4096 / 32;  // 128
  fetchA(0, aX); stageA(aX, A0);
  fetchA(1, aX); fetchA(2, aY);
  fetchB(0, bR0, bR1); fetchB(1, bS0, bS1);
  LBAR();
  for (int t = 0; t < NT; t += 2) {
    stageA(aX, A1);
    if (t + 3 < NT) fetchA(t + 3, aX);
    compute(A0, bR0, bR1);
    if (t + 2 < NT) fetchB(t + 2, bR0, bR1);
    LBAR();
    stageA(aY, A0);
    if (t + 4 < NT) fetchA(t + 4, aY);
    compute(A1, bS0, bS1);
    if (t + 3 < NT) fetchB(t + 3, bS0, bS1);
    LBAR();
  }

  // write f32 partials: part[kp][row][col]
  float* pp = part + (size_t)kp * NN * 256;
#pragma unroll
  for (int n = 0; n < 2; ++n) {
    int cl = 32 * w + 16 * n + ln;
#pragma unroll
    for (int m = 0; m < 8; ++m)
#pragma unroll
      for (int i = 0; i < 4; ++i) {
        int rr = row0 + 16 * m + 4 * g + i;
        pp[(size_t)rr * 256 + cl] = acc[m][n][i];
      }
  }
}

// ---------------- stage 3b: g1 = relu(p0+p1+p2+p3+gb1); t2 = g1 @ gw2; write t2T
__global__ __launch_bounds__(256)
void k_gcn1b(const float* __restrict__ part, const float* __restrict__ gb1,
             const bf16_t* __restrict__ gw2T, bf16_t* __restrict__ t2T) {
  __shared__ __align__(16) bf16_t g1s[64 * 264];   // 33792 B
  __shared__ __align__(16) bf16_t w2s[32 * 264];   // 16896 B
  const int tid = threadIdx.x;
  const int lane = tid & 63, w = tid >> 6;         // w: 0..3
  const int ln = lane & 15, g = lane >> 4;
  const int row0 = blockIdx.x * 64;

  for (int i = tid; i < 32 * 256; i += 256) {
    int rr = i >> 8, s = i & 255;
    w2s[rr * 264 + s] = gw2T[i];
  }

  {
    const int r = tid >> 2, q = tid & 3, c0 = q * 64;
    const float* p0 = part + (size_t)(row0 + r) * 256 + c0;
    const size_t slab = (size_t)NN * 256;
#pragma unroll
    for (int j = 0; j < 8; ++j) {
      int c = c0 + j * 8;
      float4 g0 = *(const float4*)(gb1 + c);
      float4 g1v = *(const float4*)(gb1 + c + 4);
      float s0 = g0.x, s1 = g0.y, s2 = g0.z, s3 = g0.w;
      float s4 = g1v.x, s5 = g1v.y, s6 = g1v.z, s7 = g1v.w;
#pragma unroll
      for (int p = 0; p < 4; ++p) {
        float4 u0 = *(const float4*)(p0 + p * slab + j * 8);
        float4 u1 = *(const float4*)(p0 + p * slab + j * 8 + 4);
        s0 += u0.x; s1 += u0.y; s2 += u0.z; s3 += u0.w;
        s4 += u1.x; s5 += u1.y; s6 += u1.z; s7 += u1.w;
      }
      bf16x8 o;
      o[0] = (bf16_t)(s0 > 0.f ? s0 : 0.f);
      o[1] = (bf16_t)(s1 > 0.f ? s1 : 0.f);
      o[2] = (bf16_t)(s2 > 0.f ? s2 : 0.f);
      o[3] = (bf16_t)(s3 > 0.f ? s3 : 0.f);
      o[4] = (bf16_t)(s4 > 0.f ? s4 : 0.f);
      o[5] = (bf16_t)(s5 > 0.f ? s5 : 0.f);
      o[6] = (bf16_t)(s6 > 0.f ? s6 : 0.f);
      o[7] = (bf16_t)(s7 > 0.f ? s7 : 0.f);
      *(bf16x8*)&g1s[r * 264 + c] = o;
    }
  }
  __syncthreads();

  f32x4 zz = {0.f, 0.f, 0.f, 0.f};
#pragma unroll
  for (int n = 0; n < 2; ++n) {
    f32x4 macc = zz;
#pragma unroll
    for (int ks = 0; ks < 8; ++ks) {
      bf16x8 ag = *(const bf16x8*)&g1s[(16 * w + ln) * 264 + ks * 32 + 8 * g];
      bf16x8 bg = *(const bf16x8*)&w2s[(16 * n + ln) * 264 + ks * 32 + 8 * g];
      macc = MFMA16(macc, ag, bg);
    }
    int c2 = 16 * n + ln;
    bf16x4 p;
#pragma unroll
    for (int i = 0; i < 4; ++i) p[i] = (bf16_t)macc[i];
    *(bf16x4*)(t2T + (size_t)c2 * NN + row0 + 16 * w + 4 * g) = p;
  }
}

// ---------------- stage 4: out = log_softmax(adj @ t2 + gb2)
// (measured 203 us in round 7 — near stream ceiling)
__global__ __launch_bounds__(256, 2)
void k_gcn2(const float* __restrict__ adj, const bf16_t* __restrict__ t2T,
            const float* __restrict__ gb2, float* __restrict__ out) {
  __shared__ __align__(16) char smem[49152];
  float* Lg = (float*)smem;
  const int tid = threadIdx.x;
  const int lane = tid & 63, w = tid >> 6;
  const int ln = lane & 15, g = lane >> 4;
  const int row0 = blockIdx.x * 32;

  bf16_t* A0 = (bf16_t*)(smem + w * 12288);
  bf16_t* B0 = (bf16_t*)(smem + w * 12288 + 3072);
  bf16_t* A1 = (bf16_t*)(smem + w * 12288 + 6144);
  bf16_t* B1 = (bf16_t*)(smem + w * 12288 + 9216);

  const int ar = lane >> 1, akq = lane & 1;
  const float*  aptr = adj + (size_t)(row0 + ar) * NN + akq * 16;
  const bf16_t* bptr = t2T + (size_t)ar * NN + akq * 16;

  f32x4 zz = {0.f, 0.f, 0.f, 0.f};
  f32x4 macc[2][2];
#pragma unroll
  for (int m = 0; m < 2; ++m) { macc[m][0] = zz; macc[m][1] = zz; }

  const int kb0 = w * 4096;

  float4 ra0, ra1, ra2, ra3; bf16x8 rab0, rab1;
  float4 sa0, sa1, sa2, sa3; bf16x8 sbb0, sbb1;

  auto fetchR = [&](int s, float4& a0, float4& a1, float4& a2, float4& a3,
                    bf16x8& b0, bf16x8& b1) {
    int kb = kb0 + s * 32;
    a0 = *(const float4*)(aptr + kb);
    a1 = *(const float4*)(aptr + kb + 4);
    a2 = *(const float4*)(aptr + kb + 8);
    a3 = *(const float4*)(aptr + kb + 12);
    b0 = *(const bf16x8*)(bptr + kb);
    b1 = *(const bf16x8*)(bptr + kb + 8);
  };
  auto body = [&](const float4& a0, const float4& a1, const float4& a2, const float4& a3,
                  const bf16x8& b0, const bf16x8& b1, bf16_t* Ab, bf16_t* Bb) {
    bf16x8 av0, av1;
    av0[0]=(bf16_t)a0.x; av0[1]=(bf16_t)a0.y; av0[2]=(bf16_t)a0.z; av0[3]=(bf16_t)a0.w;
    av0[4]=(bf16_t)a1.x; av0[5]=(bf16_t)a1.y; av0[6]=(bf16_t)a1.z; av0[7]=(bf16_t)a1.w;
    av1[0]=(bf16_t)a2.x; av1[1]=(bf16_t)a2.y; av1[2]=(bf16_t)a2.z; av1[3]=(bf16_t)a2.w;
    av1[4]=(bf16_t)a3.x; av1[5]=(bf16_t)a3.y; av1[6]=(bf16_t)a3.z; av1[7]=(bf16_t)a3.w;
    *(bf16x8*)&Ab[ar * 48 + akq * 16] = av0;
    *(bf16x8*)&Ab[ar * 48 + akq * 16 + 8] = av1;
    *(bf16x8*)&Bb[ar * 48 + akq * 16] = b0;
    *(bf16x8*)&Bb[ar * 48 + akq * 16 + 8] = b1;
    bf16x8 af[2], bfr[2];
#pragma unroll
    for (int m = 0; m < 2; ++m) af[m] = *(const bf16x8*)&Ab[(16 * m + ln) * 48 + 8 * g];
#pragma unroll
    for (int n = 0; n < 2; ++n) bfr[n] = *(const bf16x8*)&Bb[(16 * n + ln) * 48 + 8 * g];
#pragma unroll
    for (int m = 0; m < 2; ++m)
#pragma unroll
      for (int n = 0; n < 2; ++n)
        macc[m][n] = MFMA16(macc[m][n], af[m], bfr[n]);
  };

  fetchR(0, ra0, ra1, ra2, ra3, rab0, rab1);
  fetchR(1, sa0, sa1, sa2, sa3, sbb0, sbb1);

  for (int s = 0; s < 128; s += 2) {
    {
      bf16x8 tb0 = rab0, tb1 = rab1;
      float4 t0 = ra0, t1 = ra1, t2 = ra2, t3 = ra3;
      if (s + 2 < 128) fetchR(s + 2, ra0, ra1, ra2, ra3, rab0, rab1);
      body(t0, t1, t2, t3, tb0, tb1, A0, B0);
    }
    {
      bf16x8 tb0 = sbb0, tb1 = sbb1;
      float4 t0 = sa0, t1 = sa1, t2 = sa2, t3 = sa3;
      if (s + 3 < 128) fetchR(s + 3, sa0, sa1, sa2, sa3, sbb0, sbb1);
      body(t0, t1, t2, t3, tb0, tb1, A1, B1);
    }
  }

  __syncthreads();
#pragma unroll
  for (int m = 0; m < 2; ++m)
#pragma unroll
    for (int n = 0; n < 2; ++n)
#pragma unroll
      for (int i = 0; i < 4; ++i) {
        int rl = 16 * m + 4 * g + i;
        int cl = 16 * n + ln;
        Lg[(w * 32 + rl) * 32 + cl] = macc[m][n][i];
      }
  __syncthreads();

  int rr = tid >> 3, cg = tid & 7;
  float l4[4];
#pragma unroll
  for (int j = 0; j < 4; ++j) {
    int c = cg * 4 + j;
    l4[j] = Lg[rr * 32 + c] + Lg[(32 + rr) * 32 + c] +
            Lg[(64 + rr) * 32 + c] + Lg[(96 + rr) * 32 + c] + gb2[c];
  }
  float mx = fmaxf(fmaxf(l4[0], l4[1]), fmaxf(l4[2], l4[3]));
  mx = fmaxf(mx, __shfl_xor(mx, 1));
  mx = fmaxf(mx, __shfl_xor(mx, 2));
  mx = fmaxf(mx, __shfl_xor(mx, 4));
  float se = 0.f;
#pragma unroll
  for (int j = 0; j < 4; ++j) se += expf(l4[j] - mx);
  se += __shfl_xor(se, 1);
  se += __shfl_xor(se, 2);
  se += __shfl_xor(se, 4);
  float lse = mx + logf(se);
  float4 o;
  o.x = l4[0] - lse; o.y = l4[1] - lse; o.z = l4[2] - lse; o.w = l4[3] - lse;
  *(float4*)&out[(size_t)(row0 + rr) * 32 + cg * 4] = o;
}

extern "C" void kernel_launch(void* const* d_in, const int* in_sizes, int n_in,
                              void* d_out, int out_size, void* d_ws, size_t ws_size,
                              hipStream_t stream) {
  const float* x   = (const float*)d_in[0];
  const float* adj = (const float*)d_in[1];
  const float* W1  = (const float*)d_in[2];
  const float* b1  = (const float*)d_in[3];
  const float* W2  = (const float*)d_in[4];
  const float* b2  = (const float*)d_in[5];
  const float* W3  = (const float*)d_in[6];
  const float* b3  = (const float*)d_in[7];
  const float* gw1 = (const float*)d_in[8];
  const float* gb1 = (const float*)d_in[9];
  const float* gw2 = (const float*)d_in[10];
  const float* gb2 = (const float*)d_in[11];
  float* out = (float*)d_out;

  char* ws = (char*)d_ws;
  size_t off = 0;
  auto alloc = [&](size_t bytes) { char* p = ws + off; off += (bytes + 255) & ~(size_t)255; return p; };
  bf16_t* W1T  = (bf16_t*)alloc((size_t)256 * 2048 * 2);
  bf16_t* W2T  = (bf16_t*)alloc((size_t)256 * 2048 * 2);
  bf16_t* W3T  = (bf16_t*)alloc((size_t)256 * 1024 * 2);
  bf16_t* gw1T = (bf16_t*)alloc((size_t)256 * 768 * 2);
  bf16_t* gw2T = (bf16_t*)alloc((size_t)32 * 256 * 2);
  bf16_t* h    = (bf16_t*)alloc((size_t)NN * HD * 2);
  bf16_t* t1T  = (bf16_t*)alloc((size_t)256 * NN * 2);
  bf16_t* t2T  = (bf16_t*)alloc((size_t)32 * NN * 2);
  float*  part = (float*)alloc((size_t)4 * NN * 256 * 4);   // 64 MB f32 partials
  (void)W2T; (void)W3T;
  if (ws_size < off) return;

  k_prep_t<<<372, 256, 0, stream>>>(W1, W2, W3, gw1, gw2, W1T);

  k_branch_mlp<<<dim3(256, 3), 256, 0, stream>>>(x, W1T, W2T, W3T, b1, b2, b3, h);
  k_t1<<<256, 256, 0, stream>>>(h, gw1T, t1T);
  k_gcn1a<<<512, 512, 0, stream>>>(adj, t1T, part);
  k_gcn1b<<<256, 256, 0, stream>>>(part, gb1, gw2T, t2T);
  k_gcn2<<<512, 256, 0, stream>>>(adj, t2T, gb2, out);
}

// Round 10
// 704.833 us; speedup vs baseline: 1.4765x; 1.0005x over previous
//
#include <hip/hip_runtime.h>
#include <hip/hip_bf16.h>
#include <stdint.h>

typedef __bf16 bf16_t;
typedef bf16_t bf16x8 __attribute__((ext_vector_type(8)));
typedef bf16_t bf16x4 __attribute__((ext_vector_type(4)));
typedef float f32x4 __attribute__((ext_vector_type(4)));

#define MFMA16(acc, a, b) __builtin_amdgcn_mfma_f32_16x16x32_bf16((a), (b), (acc), 0, 0, 0)

// light barrier: waits LDS ops only; global register prefetches stay in flight
#define LBAR() do { asm volatile("s_waitcnt lgkmcnt(0)" ::: "memory"); \
  __builtin_amdgcn_s_barrier(); asm volatile("" ::: "memory"); } while (0)

#define NN 16384
#define XC 5000
#define HD 768

// ---------------- prep: LDS-tiled transpose (coalesced read AND write).
__global__ __launch_bounds__(256)
void k_prep_t(const float* __restrict__ W1, const float* __restrict__ W2,
              const float* __restrict__ W3, const float* __restrict__ gw1,
              const float* __restrict__ gw2, bf16_t* __restrict__ dst) {
  __shared__ float tl[64][65];
  int bid = blockIdx.x;
  const float* src; int K, C, Kpad, tk, base, lt;
  if (bid < 128)      { src = W1;  K = 2000; C = 256; Kpad = 2048; tk = 32; base = 0;       lt = bid; }
  else if (bid < 256) { src = W2;  K = 2000; C = 256; Kpad = 2048; tk = 32; base = 524288;  lt = bid - 128; }
  else if (bid < 320) { src = W3;  K = 1000; C = 256; Kpad = 1024; tk = 16; base = 1048576; lt = bid - 256; }
  else if (bid < 368) { src = gw1; K = 768;  C = 256; Kpad = 768;  tk = 12; base = 1310720; lt = bid - 320; }
  else                { src = gw2; K = 256;  C = 32;  Kpad = 256;  tk = 4;  base = 1507328; lt = bid - 368; }
  int tc = lt / tk, tkk = lt - tc * tk;
  int c0 = tc * 64, k0 = tkk * 64;
  int tid = threadIdx.x;
  int cl = tid & 63, rh = tid >> 6;
#pragma unroll
  for (int r = 0; r < 16; ++r) {
    int kp = k0 + r * 4 + rh;
    int c  = c0 + cl;
    float v = (kp < K && c < C) ? src[(size_t)kp * C + c] : 0.0f;   // coalesced in c
    tl[r * 4 + rh][cl] = v;
  }
  __syncthreads();
#pragma unroll
  for (int r = 0; r < 16; ++r) {
    int c = c0 + r * 4 + rh;
    if (c < C) dst[base + (size_t)c * Kpad + k0 + cl] = (bf16_t)tl[cl][r * 4 + rh];  // coalesced in kp
  }
}

// ---------------- stage 1: h[:, br*256+c] = relu(x_slice @ Wbr + bbr)   (bf16 out)
__global__ __launch_bounds__(256, 2)
void k_branch_mlp(const float* __restrict__ x,
                  const bf16_t* __restrict__ W1T, const bf16_t* __restrict__ W2T,
                  const bf16_t* __restrict__ W3T,
                  const float* __restrict__ b1, const float* __restrict__ b2,
                  const float* __restrict__ b3,
                  bf16_t* __restrict__ h) {
  __shared__ __align__(16) bf16_t smem[2 * (64 * 48 + 256 * 48)];  // 61440 B
  bf16_t* A0 = smem;
  bf16_t* B0 = smem + 64 * 48;
  bf16_t* A1 = smem + 64 * 48 + 256 * 48;
  bf16_t* B1 = A1 + 64 * 48;

  const int tid = threadIdx.x;
  const int lane = tid & 63, w = tid >> 6;
  const int ln = lane & 15, g = lane >> 4;
  const int row0 = blockIdx.x * 64;
  const int br = blockIdx.y;

  int Klim, Kpad, Foff;
  const bf16_t* BT; const float* bias;
  if (br == 0)      { Klim = 2000; Kpad = 2048; Foff = 0;    BT = W1T; bias = b1; }
  else if (br == 1) { Klim = 2000; Kpad = 2048; Foff = 2000; BT = W2T; bias = b2; }
  else              { Klim = 1000; Kpad = 1024; Foff = 4000; BT = W3T; bias = b3; }

  const int ar = tid >> 2, akq = tid & 3;  // A row 0..63, 8-f32 quarter
  const float* aptr = x + (size_t)(row0 + ar) * XC + Foff;
  const bf16_t* bptr = BT + (size_t)tid * Kpad;

  f32x4 zz = {0.f, 0.f, 0.f, 0.f};
  f32x4 acc[4][4];
#pragma unroll
  for (int m = 0; m < 4; ++m)
#pragma unroll
    for (int n = 0; n < 4; ++n) acc[m][n] = zz;

  float ra[8]; bf16x8 rb[4];   // reg set A
  float sa[8]; bf16x8 sb[4];   // reg set B

  auto fetchR = [&](int t, float* a, bf16x8* b) {
    int k0 = t * 32;
    int kk = k0 + akq * 8;
    if (kk + 8 <= Klim) {
      float4 v0 = *(const float4*)(aptr + kk);
      float4 v1 = *(const float4*)(aptr + kk + 4);
      a[0]=v0.x; a[1]=v0.y; a[2]=v0.z; a[3]=v0.w;
      a[4]=v1.x; a[5]=v1.y; a[6]=v1.z; a[7]=v1.w;
    } else {
#pragma unroll
      for (int j = 0; j < 8; ++j) a[j] = (kk + j < Klim) ? aptr[kk + j] : 0.0f;
    }
#pragma unroll
    for (int q = 0; q < 4; ++q) b[q] = *(const bf16x8*)(bptr + k0 + q * 8);
  };
  auto stage = [&](const float* a, const bf16x8* b, bf16_t* Ad, bf16_t* Bd) {
    bf16x8 av;
#pragma unroll
    for (int j = 0; j < 8; ++j) av[j] = (bf16_t)a[j];
    *(bf16x8*)&Ad[ar * 48 + akq * 8] = av;
#pragma unroll
    for (int q = 0; q < 4; ++q) *(bf16x8*)&Bd[tid * 48 + q * 8] = b[q];
  };
  auto compute = [&](const bf16_t* Ac, const bf16_t* Bc) {
    bf16x8 af[4], bfr[4];
#pragma unroll
    for (int m = 0; m < 4; ++m) af[m] = *(const bf16x8*)&Ac[(16 * m + ln) * 48 + 8 * g];
#pragma unroll
    for (int n = 0; n < 4; ++n) bfr[n] = *(const bf16x8*)&Bc[(64 * w + 16 * n + ln) * 48 + 8 * g];
#pragma unroll
    for (int m = 0; m < 4; ++m)
#pragma unroll
      for (int n = 0; n < 4; ++n)
        acc[m][n] = MFMA16(acc[m][n], af[m], bfr[n]);
  };

  const int NT = Kpad / 32;  // 64 or 32
  fetchR(0, ra, rb);
  stage(ra, rb, A0, B0);
  fetchR(1, ra, rb);
  fetchR(2, sa, sb);
  LBAR();
  for (int t = 0; t < NT; t += 2) {
    stage(ra, rb, A1, B1);
    if (t + 3 < NT) fetchR(t + 3, ra, rb);
    compute(A0, B0);
    LBAR();
    if (t + 2 < NT) stage(sa, sb, A0, B0);
    if (t + 4 < NT) fetchR(t + 4, sa, sb);
    compute(A1, B1);
    LBAR();
  }

#pragma unroll
  for (int n = 0; n < 4; ++n) {
    int cl = 64 * w + 16 * n + ln;
    float bv = bias[cl];
    int hcol = br * 256 + cl;
#pragma unroll
    for (int m = 0; m < 4; ++m)
#pragma unroll
      for (int i = 0; i < 4; ++i) {
        int rr = row0 + 16 * m + 4 * g + i;
        float v = acc[m][n][i] + bv;
        h[(size_t)rr * HD + hcol] = (bf16_t)(v > 0.f ? v : 0.f);
      }
  }
}

// ---------------- stage 2: t1 = h @ gw1; writes t1T[c][row] (bf16, transposed)
__global__ __launch_bounds__(256, 2)
void k_t1(const bf16_t* __restrict__ h, const bf16_t* __restrict__ gw1T,
          bf16_t* __restrict__ t1T) {
  __shared__ __align__(16) bf16_t smem[2 * (64 * 48 + 256 * 48)];
  bf16_t* A0 = smem;
  bf16_t* B0 = smem + 64 * 48;
  bf16_t* A1 = smem + 64 * 48 + 256 * 48;
  bf16_t* B1 = A1 + 64 * 48;

  const int tid = threadIdx.x;
  const int lane = tid & 63, w = tid >> 6;
  const int ln = lane & 15, g = lane >> 4;
  const int row0 = blockIdx.x * 64;
  const int ar = tid >> 2, akq = tid & 3;
  const bf16_t* aptr = h + (size_t)(row0 + ar) * HD;
  const bf16_t* bptr = gw1T + (size_t)tid * HD;

  f32x4 zz = {0.f, 0.f, 0.f, 0.f};
  f32x4 acc[4][4];
#pragma unroll
  for (int m = 0; m < 4; ++m)
#pragma unroll
    for (int n = 0; n < 4; ++n) acc[m][n] = zz;

  bf16x8 ra; bf16x8 rb[4];
  bf16x8 sa; bf16x8 sb[4];

  auto fetchR = [&](int t, bf16x8& a, bf16x8* b) {
    int k0 = t * 32;
    a = *(const bf16x8*)(aptr + k0 + akq * 8);
#pragma unroll
    for (int q = 0; q < 4; ++q) b[q] = *(const bf16x8*)(bptr + k0 + q * 8);
  };
  auto stage = [&](const bf16x8& a, const bf16x8* b, bf16_t* Ad, bf16_t* Bd) {
    *(bf16x8*)&Ad[ar * 48 + akq * 8] = a;
#pragma unroll
    for (int q = 0; q < 4; ++q) *(bf16x8*)&Bd[tid * 48 + q * 8] = b[q];
  };
  auto compute = [&](const bf16_t* Ac, const bf16_t* Bc) {
    bf16x8 af[4], bfr[4];
#pragma unroll
    for (int m = 0; m < 4; ++m) af[m] = *(const bf16x8*)&Ac[(16 * m + ln) * 48 + 8 * g];
#pragma unroll
    for (int n = 0; n < 4; ++n) bfr[n] = *(const bf16x8*)&Bc[(64 * w + 16 * n + ln) * 48 + 8 * g];
#pragma unroll
    for (int m = 0; m < 4; ++m)
#pragma unroll
      for (int n = 0; n < 4; ++n)
        acc[m][n] = MFMA16(acc[m][n], af[m], bfr[n]);
  };

  const int NT = HD / 32;  // 24
  fetchR(0, ra, rb);
  stage(ra, rb, A0, B0);
  fetchR(1, ra, rb);
  fetchR(2, sa, sb);
  LBAR();
  for (int t = 0; t < NT; t += 2) {
    stage(ra, rb, A1, B1);
    if (t + 3 < NT) fetchR(t + 3, ra, rb);
    compute(A0, B0);
    LBAR();
    if (t + 2 < NT) stage(sa, sb, A0, B0);
    if (t + 4 < NT) fetchR(t + 4, sa, sb);
    compute(A1, B1);
    LBAR();
  }

#pragma unroll
  for (int n = 0; n < 4; ++n) {
    int c = 64 * w + 16 * n + ln;
#pragma unroll
    for (int m = 0; m < 4; ++m) {
      bf16x4 p;
#pragma unroll
      for (int i = 0; i < 4; ++i) p[i] = (bf16_t)acc[m][n][i];
      *(bf16x4*)(t1T + (size_t)c * NN + row0 + 16 * m + 4 * g) = p;
    }
  }
}

// ---------------- stage 3a: partial[kp] = adj[:, kslice] @ t1[kslice, :]
// 512 thr (8 waves as 2M x 4N), BM=256, BN=256, K=4096/block, grid 256
// (64 rb x 4 kp, kp = bid&3 -> one 2 MB t1T slice per XCD, 64-block reuse).
// t1T traffic = 256 blocks x 2 MB = 512 MB (half of BM=128).
__global__ __launch_bounds__(512, 2)
void k_gcn1a(const float* __restrict__ adj, const bf16_t* __restrict__ t1T,
             float* __restrict__ part) {
  __shared__ __align__(16) bf16_t smem[2 * 256 * 48];   // 48 KB
  bf16_t* A0 = smem;
  bf16_t* A1 = smem + 256 * 48;

  const int tid = threadIdx.x;
  const int lane = tid & 63, w = tid >> 6;      // w: 0..7
  const int ln = lane & 15, g = lane >> 4;
  const int wm = w >> 2, wn = w & 3;            // 2 M-waves x 4 N-waves

  const int bid = blockIdx.x;
  const int kp = bid & 3;                       // K-slice 0..3 (pinned per XCD)
  const int rb = bid >> 2;                      // row-block 0..63
  const int row0 = rb * 256;
  const int kbase = kp * 4096;

  const int ar = tid >> 1, ah = (tid & 1) * 16;   // A: row 0..255, 16-elem K-half
  const float*  aptr = adj + (size_t)(row0 + ar) * NN + kbase + ah;
  const bf16_t* bB = t1T + (size_t)(64 * wn + ln) * NN + kbase + 8 * g;

  f32x4 zz = {0.f, 0.f, 0.f, 0.f};
  f32x4 acc[8][4];
#pragma unroll
  for (int m = 0; m < 8; ++m)
#pragma unroll
    for (int n = 0; n < 4; ++n) acc[m][n] = zz;

  float aX[16], aY[16];
  bf16x8 bR[4], bS[4];

  auto fetchA = [&](int t, float* a) {
    const float* p = aptr + t * 32;
#pragma unroll
    for (int q = 0; q < 4; ++q) {
      float4 v = *(const float4*)(p + q * 4);
      a[q*4+0]=v.x; a[q*4+1]=v.y; a[q*4+2]=v.z; a[q*4+3]=v.w;
    }
  };
  auto fetchB = [&](int t, bf16x8* b) {
    int k0 = t * 32;
#pragma unroll
    for (int n = 0; n < 4; ++n) b[n] = *(const bf16x8*)(bB + (size_t)16 * n * NN + k0);
  };
  auto stageA = [&](const float* a, bf16_t* Ad) {
    bf16x8 av0, av1;
#pragma unroll
    for (int j = 0; j < 8; ++j) { av0[j] = (bf16_t)a[j]; av1[j] = (bf16_t)a[8 + j]; }
    *(bf16x8*)&Ad[ar * 48 + ah] = av0;
    *(bf16x8*)&Ad[ar * 48 + ah + 8] = av1;
  };
  auto compute = [&](const bf16_t* Ac, const bf16x8* b) {
#pragma unroll
    for (int m = 0; m < 8; ++m) {
      bf16x8 af = *(const bf16x8*)&Ac[(128 * wm + 16 * m + ln) * 48 + 8 * g];
#pragma unroll
      for (int n = 0; n < 4; ++n)
        acc[m][n] = MFMA16(acc[m][n], af, b[n]);
    }
  };

  const int NT = 4096 / 32;  // 128
  fetchA(0, aX); stageA(aX, A0);
  fetchA(1, aX); fetchA(2, aY);
  fetchB(0, bR); fetchB(1, bS);
  LBAR();
  for (int t = 0; t < NT; t += 2) {
    stageA(aX, A1);
    if (t + 3 < NT) fetchA(t + 3, aX);
    compute(A0, bR);
    if (t + 2 < NT) fetchB(t + 2, bR);
    LBAR();
    stageA(aY, A0);
    if (t + 4 < NT) fetchA(t + 4, aY);
    compute(A1, bS);
    if (t + 3 < NT) fetchB(t + 3, bS);
    LBAR();
  }

  // write f32 partials: part[kp][row][col]
  float* pp = part + (size_t)kp * NN * 256;
#pragma unroll
  for (int n = 0; n < 4; ++n) {
    int cl = 64 * wn + 16 * n + ln;
#pragma unroll
    for (int m = 0; m < 8; ++m)
#pragma unroll
      for (int i = 0; i < 4; ++i) {
        int rr = row0 + 128 * wm + 16 * m + 4 * g + i;
        pp[(size_t)rr * 256 + cl] = acc[m][n][i];
      }
  }
}

// ---------------- stage 3b: g1 = relu(p0+p1+p2+p3+gb1); t2 = g1 @ gw2; write t2T
__global__ __launch_bounds__(256)
void k_gcn1b(const float* __restrict__ part, const float* __restrict__ gb1,
             const bf16_t* __restrict__ gw2T, bf16_t* __restrict__ t2T) {
  __shared__ __align__(16) bf16_t g1s[64 * 264];   // 33792 B
  __shared__ __align__(16) bf16_t w2s[32 * 264];   // 16896 B
  const int tid = threadIdx.x;
  const int lane = tid & 63, w = tid >> 6;         // w: 0..3
  const int ln = lane & 15, g = lane >> 4;
  const int row0 = blockIdx.x * 64;

  for (int i = tid; i < 32 * 256; i += 256) {
    int rr = i >> 8, s = i & 255;
    w2s[rr * 264 + s] = gw2T[i];
  }

  {
    const int r = tid >> 2, q = tid & 3, c0 = q * 64;
    const float* p0 = part + (size_t)(row0 + r) * 256 + c0;
    const size_t slab = (size_t)NN * 256;
#pragma unroll
    for (int j = 0; j < 8; ++j) {
      int c = c0 + j * 8;
      float4 g0 = *(const float4*)(gb1 + c);
      float4 g1v = *(const float4*)(gb1 + c + 4);
      float s0 = g0.x, s1 = g0.y, s2 = g0.z, s3 = g0.w;
      float s4 = g1v.x, s5 = g1v.y, s6 = g1v.z, s7 = g1v.w;
#pragma unroll
      for (int p = 0; p < 4; ++p) {
        float4 u0 = *(const float4*)(p0 + p * slab + j * 8);
        float4 u1 = *(const float4*)(p0 + p * slab + j * 8 + 4);
        s0 += u0.x; s1 += u0.y; s2 += u0.z; s3 += u0.w;
        s4 += u1.x; s5 += u1.y; s6 += u1.z; s7 += u1.w;
      }
      bf16x8 o;
      o[0] = (bf16_t)(s0 > 0.f ? s0 : 0.f);
      o[1] = (bf16_t)(s1 > 0.f ? s1 : 0.f);
      o[2] = (bf16_t)(s2 > 0.f ? s2 : 0.f);
      o[3] = (bf16_t)(s3 > 0.f ? s3 : 0.f);
      o[4] = (bf16_t)(s4 > 0.f ? s4 : 0.f);
      o[5] = (bf16_t)(s5 > 0.f ? s5 : 0.f);
      o[6] = (bf16_t)(s6 > 0.f ? s6 : 0.f);
      o[7] = (bf16_t)(s7 > 0.f ? s7 : 0.f);
      *(bf16x8*)&g1s[r * 264 + c] = o;
    }
  }
  __syncthreads();

  f32x4 zz = {0.f, 0.f, 0.f, 0.f};
#pragma unroll
  for (int n = 0; n < 2; ++n) {
    f32x4 macc = zz;
#pragma unroll
    for (int ks = 0; ks < 8; ++ks) {
      bf16x8 ag = *(const bf16x8*)&g1s[(16 * w + ln) * 264 + ks * 32 + 8 * g];
      bf16x8 bg = *(const bf16x8*)&w2s[(16 * n + ln) * 264 + ks * 32 + 8 * g];
      macc = MFMA16(macc, ag, bg);
    }
    int c2 = 16 * n + ln;
    bf16x4 p;
#pragma unroll
    for (int i = 0; i < 4; ++i) p[i] = (bf16_t)macc[i];
    *(bf16x4*)(t2T + (size_t)c2 * NN + row0 + 16 * w + 4 * g) = p;
  }
}

// ---------------- stage 4: out = log_softmax(adj @ t2 + gb2)
// (measured 203 us in round 7 — near stream ceiling)
__global__ __launch_bounds__(256, 2)
void k_gcn2(const float* __restrict__ adj, const bf16_t* __restrict__ t2T,
            const float* __restrict__ gb2, float* __restrict__ out) {
  __shared__ __align__(16) char smem[49152];
  float* Lg = (float*)smem;
  const int tid = threadIdx.x;
  const int lane = tid & 63, w = tid >> 6;
  const int ln = lane & 15, g = lane >> 4;
  const int row0 = blockIdx.x * 32;

  bf16_t* A0 = (bf16_t*)(smem + w * 12288);
  bf16_t* B0 = (bf16_t*)(smem + w * 12288 + 3072);
  bf16_t* A1 = (bf16_t*)(smem + w * 12288 + 6144);
  bf16_t* B1 = (bf16_t*)(smem + w * 12288 + 9216);

  const int ar = lane >> 1, akq = lane & 1;
  const float*  aptr = adj + (size_t)(row0 + ar) * NN + akq * 16;
  const bf16_t* bptr = t2T + (size_t)ar * NN + akq * 16;

  f32x4 zz = {0.f, 0.f, 0.f, 0.f};
  f32x4 macc[2][2];
#pragma unroll
  for (int m = 0; m < 2; ++m) { macc[m][0] = zz; macc[m][1] = zz; }

  const int kb0 = w * 4096;

  float4 ra0, ra1, ra2, ra3; bf16x8 rab0, rab1;
  float4 sa0, sa1, sa2, sa3; bf16x8 sbb0, sbb1;

  auto fetchR = [&](int s, float4& a0, float4& a1, float4& a2, float4& a3,
                    bf16x8& b0, bf16x8& b1) {
    int kb = kb0 + s * 32;
    a0 = *(const float4*)(aptr + kb);
    a1 = *(const float4*)(aptr + kb + 4);
    a2 = *(const float4*)(aptr + kb + 8);
    a3 = *(const float4*)(aptr + kb + 12);
    b0 = *(const bf16x8*)(bptr + kb);
    b1 = *(const bf16x8*)(bptr + kb + 8);
  };
  auto body = [&](const float4& a0, const float4& a1, const float4& a2, const float4& a3,
                  const bf16x8& b0, const bf16x8& b1, bf16_t* Ab, bf16_t* Bb) {
    bf16x8 av0, av1;
    av0[0]=(bf16_t)a0.x; av0[1]=(bf16_t)a0.y; av0[2]=(bf16_t)a0.z; av0[3]=(bf16_t)a0.w;
    av0[4]=(bf16_t)a1.x; av0[5]=(bf16_t)a1.y; av0[6]=(bf16_t)a1.z; av0[7]=(bf16_t)a1.w;
    av1[0]=(bf16_t)a2.x; av1[1]=(bf16_t)a2.y; av1[2]=(bf16_t)a2.z; av1[3]=(bf16_t)a2.w;
    av1[4]=(bf16_t)a3.x; av1[5]=(bf16_t)a3.y; av1[6]=(bf16_t)a3.z; av1[7]=(bf16_t)a3.w;
    *(bf16x8*)&Ab[ar * 48 + akq * 16] = av0;
    *(bf16x8*)&Ab[ar * 48 + akq * 16 + 8] = av1;
    *(bf16x8*)&Bb[ar * 48 + akq * 16] = b0;
    *(bf16x8*)&Bb[ar * 48 + akq * 16 + 8] = b1;
    bf16x8 af[2], bfr[2];
#pragma unroll
    for (int m = 0; m < 2; ++m) af[m] = *(const bf16x8*)&Ab[(16 * m + ln) * 48 + 8 * g];
#pragma unroll
    for (int n = 0; n < 2; ++n) bfr[n] = *(const bf16x8*)&Bb[(16 * n + ln) * 48 + 8 * g];
#pragma unroll
    for (int m = 0; m < 2; ++m)
#pragma unroll
      for (int n = 0; n < 2; ++n)
        macc[m][n] = MFMA16(macc[m][n], af[m], bfr[n]);
  };

  fetchR(0, ra0, ra1, ra2, ra3, rab0, rab1);
  fetchR(1, sa0, sa1, sa2, sa3, sbb0, sbb1);

  for (int s = 0; s < 128; s += 2) {
    {
      bf16x8 tb0 = rab0, tb1 = rab1;
      float4 t0 = ra0, t1 = ra1, t2 = ra2, t3 = ra3;
      if (s + 2 < 128) fetchR(s + 2, ra0, ra1, ra2, ra3, rab0, rab1);
      body(t0, t1, t2, t3, tb0, tb1, A0, B0);
    }
    {
      bf16x8 tb0 = sbb0, tb1 = sbb1;
      float4 t0 = sa0, t1 = sa1, t2 = sa2, t3 = sa3;
      if (s + 3 < 128) fetchR(s + 3, sa0, sa1, sa2, sa3, sbb0, sbb1);
      body(t0, t1, t2, t3, tb0, tb1, A1, B1);
    }
  }

  __syncthreads();
#pragma unroll
  for (int m = 0; m < 2; ++m)
#pragma unroll
    for (int n = 0; n < 2; ++n)
#pragma unroll
      for (int i = 0; i < 4; ++i) {
        int rl = 16 * m + 4 * g + i;
        int cl = 16 * n + ln;
        Lg[(w * 32 + rl) * 32 + cl] = macc[m][n][i];
      }
  __syncthreads();

  int rr = tid >> 3, cg = tid & 7;
  float l4[4];
#pragma unroll
  for (int j = 0; j < 4; ++j) {
    int c = cg * 4 + j;
    l4[j] = Lg[rr * 32 + c] + Lg[(32 + rr) * 32 + c] +
            Lg[(64 + rr) * 32 + c] + Lg[(96 + rr) * 32 + c] + gb2[c];
  }
  float mx = fmaxf(fmaxf(l4[0], l4[1]), fmaxf(l4[2], l4[3]));
  mx = fmaxf(mx, __shfl_xor(mx, 1));
  mx = fmaxf(mx, __shfl_xor(mx, 2));
  mx = fmaxf(mx, __shfl_xor(mx, 4));
  float se = 0.f;
#pragma unroll
  for (int j = 0; j < 4; ++j) se += expf(l4[j] - mx);
  se += __shfl_xor(se, 1);
  se += __shfl_xor(se, 2);
  se += __shfl_xor(se, 4);
  float lse = mx + logf(se);
  float4 o;
  o.x = l4[0] - lse; o.y = l4[1] - lse; o.z = l4[2] - lse; o.w = l4[3] - lse;
  *(float4*)&out[(size_t)(row0 + rr) * 32 + cg * 4] = o;
}

extern "C" void kernel_launch(void* const* d_in, const int* in_sizes, int n_in,
                              void* d_out, int out_size, void* d_ws, size_t ws_size,
                              hipStream_t stream) {
  const float* x   = (const float*)d_in[0];
  const float* adj = (const float*)d_in[1];
  const float* W1  = (const float*)d_in[2];
  const float* b1  = (const float*)d_in[3];
  const float* W2  = (const float*)d_in[4];
  const float* b2  = (const float*)d_in[5];
  const float* W3  = (const float*)d_in[6];
  const float* b3  = (const float*)d_in[7];
  const float* gw1 = (const float*)d_in[8];
  const float* gb1 = (const float*)d_in[9];
  const float* gw2 = (const float*)d_in[10];
  const float* gb2 = (const float*)d_in[11];
  float* out = (float*)d_out;

  char* ws = (char*)d_ws;
  size_t off = 0;
  auto alloc = [&](size_t bytes) { char* p = ws + off; off += (bytes + 255) & ~(size_t)255; return p; };
  bf16_t* W1T  = (bf16_t*)alloc((size_t)256 * 2048 * 2);
  bf16_t* W2T  = (bf16_t*)alloc((size_t)256 * 2048 * 2);
  bf16_t* W3T  = (bf16_t*)alloc((size_t)256 * 1024 * 2);
  bf16_t* gw1T = (bf16_t*)alloc((size_t)256 * 768 * 2);
  bf16_t* gw2T = (bf16_t*)alloc((size_t)32 * 256 * 2);
  bf16_t* h    = (bf16_t*)alloc((size_t)NN * HD * 2);
  bf16_t* t1T  = (bf16_t*)alloc((size_t)256 * NN * 2);
  bf16_t* t2T  = (bf16_t*)alloc((size_t)32 * NN * 2);
  float*  part = (float*)alloc((size_t)4 * NN * 256 * 4);   // 64 MB f32 partials
  (void)W2T; (void)W3T;
  if (ws_size < off) return;

  k_prep_t<<<372, 256, 0, stream>>>(W1, W2, W3, gw1, gw2, W1T);

  k_branch_mlp<<<dim3(256, 3), 256, 0, stream>>>(x, W1T, W2T, W3T, b1, b2, b3, h);
  k_t1<<<256, 256, 0, stream>>>(h, gw1T, t1T);
  k_gcn1a<<<256, 512, 0, stream>>>(adj, t1T, part);
  k_gcn1b<<<256, 256, 0, stream>>>(part, gb1, gw2T, t2T);
  k_gcn2<<<512, 256, 0, stream>>>(adj, t2T, gb2, out);
}